// Round 2
// baseline (1185.777 us; speedup 1.0000x reference)
//
#include <hip/hip_runtime.h>
#include <math.h>

#define NB 16
#define NM 512
#define NT 64
#define NF 128
#define NH 128
// 3H = 384

// ---------------- prep: WxT[f][i] = sum_k mlp_w1[i][128+k]*lin_w[k][f]; linT[f][h] = lin_w[h][f]
__global__ __launch_bounds__(128) void prep_kernel(
    const float* __restrict__ lin_w, const float* __restrict__ mlp_w1,
    float* __restrict__ WxT, float* __restrict__ linT)
{
  __shared__ float col[128];
  const int f = blockIdx.x & 127;
  const int i = threadIdx.x;
  col[i] = lin_w[i * NF + f];   // lin_w[k=i, f]
  __syncthreads();
  if (blockIdx.x < 128) {
    const float* w1b = mlp_w1 + i * (2 * NH) + NH;   // W1b row i
    float s = 0.f;
#pragma unroll 16
    for (int k = 0; k < NH; k++) s += w1b[k] * col[k];
    WxT[f * 128 + i] = s;
  } else {
    linT[f * 128 + i] = col[i];
  }
}

// ---------------- main fused kernel: one block per (b,t), 128 threads (thread = i / f lane)
__global__ __launch_bounds__(128, 2) void main_kernel(
    const float* __restrict__ X, const float* __restrict__ C,
    const float* __restrict__ h_target, const float* __restrict__ distance,
    const float* __restrict__ lin_b,
    const float* __restrict__ mlp_w1, const float* __restrict__ mlp_b1,
    const float* __restrict__ mlp_w2, const float* __restrict__ mlp_b2,
    const float* __restrict__ lin2_w, const float* __restrict__ lin2_b,
    const float* __restrict__ wih0, const float* __restrict__ bih0,
    const float* __restrict__ WxT, const float* __restrict__ linT,
    float* __restrict__ gi0)
{
  const int bt = blockIdx.x;
  const int b = bt >> 6;        // NT = 64
  const int t = bt & 63;
  const int i = threadIdx.x;

  __shared__ __align__(16) float sh_ht[128];
  __shared__ __align__(16) float sh_linb[128];
  __shared__ __align__(16) float xs[2][128];
  __shared__ float partials[2];
  __shared__ float sh_lw;
  __shared__ __align__(16) float sh_vec[128];

  sh_ht[i]   = h_target[(b * NT + t) * NH + i];
  sh_linb[i] = lin_b[i];
  __syncthreads();

  // u_i = b1[i] + W1a[i,:]@h_target[b,t] + W1b[i,:]@lin_b
  float u = mlp_b1[i];
  {
    const float* w1 = mlp_w1 + i * (2 * NH);
#pragma unroll 8
    for (int k = 0; k < NH; k++)
      u += w1[k] * sh_ht[k] + w1[NH + k] * sh_linb[k];
  }

  // Wx row i in registers (coalesced: WxT[f][i])
  float wreg[128];
#pragma unroll
  for (int f = 0; f < 128; f++) wreg[f] = WxT[f * 128 + i];

  const float w2i = mlp_w2[i];
  const float c0 = lin2_w[0], c1 = lin2_w[1], c2 = lin2_w[2];
  const float lb2 = lin2_b[0];
  const float mb2 = mlp_b2[0];

  const float* Xrow = X + ((size_t)(b * NM) * NT + t) * NF + i;  // + m*NT*NF
  const float* Crow = C + (size_t)(b * NM) * NT + t;             // + m*NT

  float xagg = 0.f, lsum = 0.f;
  float xcur = Xrow[0];
  xs[0][i] = xcur;
  __syncthreads();
  int cur = 0;

  for (int m = 0; m < NM; m++) {
    float xnext = 0.f;
    if (m + 1 < NM) xnext = Xrow[(size_t)(m + 1) * NT * NF];

    // s_i = Wx[i,:] @ x  (x broadcast from LDS)
    float s0 = 0.f, s1 = 0.f, s2 = 0.f, s3 = 0.f;
    const float4* xc4 = (const float4*)xs[cur];
#pragma unroll
    for (int f = 0; f < 32; f++) {
      float4 xv = xc4[f];
      s0 += wreg[4 * f + 0] * xv.x;
      s1 += wreg[4 * f + 1] * xv.y;
      s2 += wreg[4 * f + 2] * xv.z;
      s3 += wreg[4 * f + 3] * xv.w;
    }
    float v = (s0 + s1) + (s2 + s3) + u;
    v = fmaxf(v, 0.f) * w2i;

    // reduce over i (2 waves of 64)
#pragma unroll
    for (int off = 32; off > 0; off >>= 1) v += __shfl_down(v, off, 64);
    if ((i & 63) == 0) partials[i >> 6] = v;
    __syncthreads();   // B1: partials visible
    if (i == 0) {
      float wmsg = partials[0] + partials[1] + mb2;
      sh_lw = Crow[(size_t)m * NT] * c0 + distance[m] * c1 + wmsg * c2 + lb2;
    }
    xs[cur ^ 1][i] = xnext;
    __syncthreads();   // B2: sh_lw + next x visible
    float lw = sh_lw;
    xagg += lw * xcur;
    lsum += lw;
    xcur = xnext;
    cur ^= 1;
  }

  // epilogue: h_agg = linT @ xagg + lsum*lin_b ; then gi0 = wih0 @ h_agg + bih0
  sh_vec[i] = xagg;
  __syncthreads();
  float hv = lsum * sh_linb[i];
#pragma unroll 8
  for (int f = 0; f < 128; f++) hv += linT[f * 128 + i] * sh_vec[f];
  __syncthreads();   // all reads of sh_ht (via u) long done; safe to reuse
  sh_ht[i] = hv;     // reuse as h_agg
  __syncthreads();

  const int gbase = (b * NT + t) * 384;
#pragma unroll
  for (int rr = 0; rr < 3; rr++) {
    const int j = i + rr * 128;
    const float* wrow = wih0 + j * NH;
    float g = bih0[j];
#pragma unroll 8
    for (int k = 0; k < NH; k++) g += wrow[k] * sh_ht[k];
    gi0[gbase + j] = g;
  }
}

// ---------------- gi (input-gate) GEMM for layer 1: gi[bt][j] = wih[j,:]@xin[bt] + bih[j]
__global__ __launch_bounds__(384, 2) void gi_kernel(
    const float* __restrict__ xin, const float* __restrict__ wih,
    const float* __restrict__ bih, float* __restrict__ gi)
{
  __shared__ __align__(16) float xr[128];
  const int bt = blockIdx.x;
  const int j = threadIdx.x;
  if (j < 128) xr[j] = xin[bt * 128 + j];
  __syncthreads();
  const float* wrow = wih + j * NH;
  float a0 = 0.f, a1 = 0.f, a2 = 0.f, a3 = 0.f;
#pragma unroll 8
  for (int k = 0; k < 128; k += 4) {
    a0 += wrow[k]     * xr[k];
    a1 += wrow[k + 1] * xr[k + 1];
    a2 += wrow[k + 2] * xr[k + 2];
    a3 += wrow[k + 3] * xr[k + 3];
  }
  gi[bt * 384 + j] = (a0 + a1) + (a2 + a3) + bih[j];
}

// ---------------- GRU recurrence: one block per batch, 384 threads (thread = gate-row j)
__global__ __launch_bounds__(384, 2) void gru_layer_kernel(
    const float* __restrict__ gi, const float* __restrict__ whh,
    const float* __restrict__ bhh, float* __restrict__ out)
{
  const int b = blockIdx.x;
  const int j = threadIdx.x;
  __shared__ float hs[128];
  __shared__ float ghs[384];

  float wreg[128];
#pragma unroll
  for (int k = 0; k < 128; k++) wreg[k] = whh[j * 128 + k];
  const float bh = bhh[j];
  if (j < 128) hs[j] = 0.f;
  __syncthreads();

  for (int t = 0; t < NT; t++) {
    float a0 = 0.f, a1 = 0.f, a2 = 0.f, a3 = 0.f;
#pragma unroll
    for (int k = 0; k < 128; k += 4) {
      a0 += wreg[k]     * hs[k];
      a1 += wreg[k + 1] * hs[k + 1];
      a2 += wreg[k + 2] * hs[k + 2];
      a3 += wreg[k + 3] * hs[k + 3];
    }
    ghs[j] = (a0 + a1) + (a2 + a3) + bh;
    __syncthreads();   // gh visible; dot-phase reads of hs complete
    if (j < 128) {
      const int base = (b * NT + t) * 384;
      const float gir = gi[base + j];
      const float giz = gi[base + 128 + j];
      const float gin = gi[base + 256 + j];
      const float hprev = hs[j];
      const float r = 1.f / (1.f + expf(-(gir + ghs[j])));
      const float z = 1.f / (1.f + expf(-(giz + ghs[128 + j])));
      const float n = tanhf(gin + r * ghs[256 + j]);
      const float hnew = (1.f - z) * n + z * hprev;
      hs[j] = hnew;
      out[(b * NT + t) * 128 + j] = hnew;
    }
    __syncthreads();   // h update visible for next step
  }
}

extern "C" void kernel_launch(void* const* d_in, const int* in_sizes, int n_in,
                              void* d_out, int out_size, void* d_ws, size_t ws_size,
                              hipStream_t stream)
{
  const float* X        = (const float*)d_in[0];
  const float* C        = (const float*)d_in[1];
  const float* h_target = (const float*)d_in[2];
  const float* distance = (const float*)d_in[3];
  const float* lin_w    = (const float*)d_in[4];
  const float* lin_b    = (const float*)d_in[5];
  const float* mlp_w1   = (const float*)d_in[6];
  const float* mlp_b1   = (const float*)d_in[7];
  const float* mlp_w2   = (const float*)d_in[8];
  const float* mlp_b2   = (const float*)d_in[9];
  const float* lin2_w   = (const float*)d_in[10];
  const float* lin2_b   = (const float*)d_in[11];
  const float* wih0     = (const float*)d_in[12];
  const float* whh0     = (const float*)d_in[13];
  const float* bih0     = (const float*)d_in[14];
  const float* bhh0     = (const float*)d_in[15];
  const float* wih1     = (const float*)d_in[16];
  const float* whh1     = (const float*)d_in[17];
  const float* bih1     = (const float*)d_in[18];
  const float* bhh1     = (const float*)d_in[19];
  float* out = (float*)d_out;

  float* ws   = (float*)d_ws;
  float* WxT  = ws;                       // 16384 floats
  float* linT = ws + 16384;               // 16384
  float* gi   = ws + 32768;               // 1024*384 = 393216
  float* out0 = ws + 32768 + 393216;      // 131072

  prep_kernel<<<256, 128, 0, stream>>>(lin_w, mlp_w1, WxT, linT);
  main_kernel<<<NB * NT, 128, 0, stream>>>(X, C, h_target, distance, lin_b,
      mlp_w1, mlp_b1, mlp_w2, mlp_b2, lin2_w, lin2_b, wih0, bih0, WxT, linT, gi);
  gru_layer_kernel<<<NB, 384, 0, stream>>>(gi, whh0, bhh0, out0);
  gi_kernel<<<NB * NT, 384, 0, stream>>>(out0, wih1, bih1, gi);
  gru_layer_kernel<<<NB, 384, 0, stream>>>(gi, whh1, bhh1, out);
}

// Round 3
// 654.058 us; speedup vs baseline: 1.8130x; 1.8130x over previous
//
#include <hip/hip_runtime.h>
#include <math.h>

#define NB 16
#define NM 512
#define NT 64
#define NF 128
#define NH 128
#define PADB 136   // padded LDS row, in bf16 elements (136*2 = 272 B = 68 dwords)

typedef short short8 __attribute__((ext_vector_type(8)));
typedef float floatx4 __attribute__((ext_vector_type(4)));

static __device__ __forceinline__ unsigned short f2b(float f) {
  union { float f; unsigned u; } v; v.f = f;
  unsigned r = v.u + 0x7fff + ((v.u >> 16) & 1);   // RNE
  return (unsigned short)(r >> 16);
}
static __device__ __forceinline__ float b2f_us(unsigned short h) {
  union { unsigned u; float f; } v; v.u = ((unsigned)h) << 16; return v.f;
}

// ---------- prep: WxBf[i][f] = bf16( sum_k mlp_w1[i][128+k]*lin_w[k][f] );  linT[f][i] = lin_w[i][f]
__global__ __launch_bounds__(128) void prep_kernel(
    const float* __restrict__ lin_w, const float* __restrict__ mlp_w1,
    unsigned short* __restrict__ WxBf, float* __restrict__ linT)
{
  const int tid = threadIdx.x;
  if (blockIdx.x < 128) {
    const int i = blockIdx.x;
    __shared__ float sw[128];
    sw[tid] = mlp_w1[i * 256 + 128 + tid];   // W1b row i
    __syncthreads();
    float s = 0.f;
#pragma unroll 16
    for (int k = 0; k < 128; k++) s += sw[k] * lin_w[k * 128 + tid];
    WxBf[i * 128 + tid] = f2b(s);
  } else {
    const int f = blockIdx.x - 128;
    linT[f * 128 + tid] = lin_w[tid * 128 + f];
  }
}

// ---------- u: u[bt][i] = mlp_b1[i] + W1a[i,:]@h_target[bt] + W1b[i,:]@lin_b
__global__ __launch_bounds__(128) void u_kernel(
    const float* __restrict__ h_target, const float* __restrict__ lin_b,
    const float* __restrict__ mlp_w1, const float* __restrict__ mlp_b1,
    float* __restrict__ u_out)
{
  const int bt = blockIdx.x, i = threadIdx.x;
  __shared__ float sht[128], slb[128];
  sht[i] = h_target[bt * 128 + i];
  slb[i] = lin_b[i];
  __syncthreads();
  float u = mlp_b1[i];
  const float* w1 = mlp_w1 + i * 256;
#pragma unroll 8
  for (int k = 0; k < 128; k++) u += w1[k] * sht[k] + w1[128 + k] * slb[k];
  u_out[bt * 128 + i] = u;
}

// ---------- pass1: per (bt, g): scores via MFMA -> lw -> weighted x partial sums
__global__ __launch_bounds__(256, 2) void pass1_kernel(
    const float* __restrict__ X, const float* __restrict__ C,
    const float* __restrict__ dist,
    const unsigned short* __restrict__ WxBf, const float* __restrict__ u_g,
    const float* __restrict__ mlp_w2, const float* __restrict__ mlp_b2,
    const float* __restrict__ lin2_w, const float* __restrict__ lin2_b,
    float* __restrict__ part, float* __restrict__ partls)
{
  const int blk = blockIdx.x;
  const int g = blk & 7, bt = blk >> 3;
  const int b = bt >> 6, t = bt & 63;
  const int tid = threadIdx.x;

  __shared__ unsigned short xb[64 * PADB];     // 17408 B
  __shared__ unsigned short wxb[128 * PADB];   // 34816 B
  __shared__ float u_sh[128], w2_sh[128], lw_sh[64];
  __shared__ float red[2][128];
  __shared__ float red_ls;

  // x tile: 64 rows (m = g*64+row) x 128 f, f32 -> bf16 LDS (padded rows)
  const float* Xbase = X + (((size_t)(b * NM + g * 64)) * NT + t) * NF;
#pragma unroll
  for (int p = 0; p < 8; p++) {
    int idx = p * 256 + tid;            // 0..2047 float4s
    int row = idx >> 5, c4 = idx & 31;
    float4 xv = *(const float4*)(Xbase + (size_t)row * NT * NF + c4 * 4);
    ushort4 h;
    h.x = f2b(xv.x); h.y = f2b(xv.y); h.z = f2b(xv.z); h.w = f2b(xv.w);
    *(ushort4*)&xb[row * PADB + c4 * 4] = h;
  }
  // Wx (bf16) into padded LDS
  const unsigned* wsrc = (const unsigned*)WxBf;
  unsigned* wdst = (unsigned*)wxb;
#pragma unroll
  for (int p = 0; p < 32; p++) {
    int idx = p * 256 + tid;            // 0..8191 dwords
    int row = idx >> 6, cu = idx & 63;
    wdst[row * (PADB / 2) + cu] = wsrc[idx];
  }
  if (tid < 128) { u_sh[tid] = u_g[bt * 128 + tid]; w2_sh[tid] = mlp_w2[tid]; }
  __syncthreads();

  // MFMA: wave w computes S[w*16..+16, 0..128)
  const int w = tid >> 6, lane = tid & 63;
  const int col = lane & 15, quad = lane >> 4;
  short8 afr[4];
#pragma unroll
  for (int kc = 0; kc < 4; kc++)
    afr[kc] = *(const short8*)&xb[(w * 16 + col) * PADB + kc * 32 + quad * 8];
  floatx4 acc[8];
#pragma unroll
  for (int it = 0; it < 8; it++) acc[it] = {0.f, 0.f, 0.f, 0.f};
#pragma unroll
  for (int it = 0; it < 8; it++) {
#pragma unroll
    for (int kc = 0; kc < 4; kc++) {
      short8 bfr = *(const short8*)&wxb[(it * 16 + col) * PADB + kc * 32 + quad * 8];
      acc[it] = __builtin_amdgcn_mfma_f32_16x16x32_bf16(afr[kc], bfr, acc[it], 0, 0, 0);
    }
  }

  // epilogue: v[m] = sum_i w2[i]*relu(S[m,i]+u[i]); reduce over col (low 4 lane bits)
  float w2l[8], ul[8];
#pragma unroll
  for (int it = 0; it < 8; it++) { w2l[it] = w2_sh[it * 16 + col]; ul[it] = u_sh[it * 16 + col]; }
  float vsum[4];
#pragma unroll
  for (int r = 0; r < 4; r++) {
    float v = 0.f;
#pragma unroll
    for (int it = 0; it < 8; it++) {
      float s = acc[it][r] + ul[it];
      v += w2l[it] * fmaxf(s, 0.f);
    }
    v += __shfl_xor(v, 1, 64);
    v += __shfl_xor(v, 2, 64);
    v += __shfl_xor(v, 4, 64);
    v += __shfl_xor(v, 8, 64);
    vsum[r] = v;
  }
  if (col == 0) {
    const float c0 = lin2_w[0], c1 = lin2_w[1], c2 = lin2_w[2];
    const float lb2 = lin2_b[0], mb2 = mlp_b2[0];
#pragma unroll
    for (int r = 0; r < 4; r++) {
      int ml = w * 16 + quad * 4 + r;
      int m = g * 64 + ml;
      float wmsg = vsum[r] + mb2;
      lw_sh[ml] = C[((size_t)b * NM + m) * NT + t] * c0 + dist[m] * c1 + wmsg * c2 + lb2;
    }
  }
  __syncthreads();

  // weighted sum over this m-chunk
  const int f = tid & 127, half = tid >> 7;
  float xa = 0.f;
#pragma unroll 8
  for (int mm = half * 32; mm < half * 32 + 32; mm++)
    xa += lw_sh[mm] * b2f_us(xb[mm * PADB + f]);
  red[half][f] = xa;
  if (tid == 0) {
    float ls = 0.f;
    for (int mm = 0; mm < 64; mm++) ls += lw_sh[mm];
    red_ls = ls;
  }
  __syncthreads();
  if (tid < 128) part[(size_t)blk * 128 + tid] = red[0][tid] + red[1][tid];
  if (tid == 128) partls[blk] = red_ls;
}

// ---------- reduce: xagg -> h_agg -> gi0
__global__ __launch_bounds__(384) void reduce_kernel(
    const float* __restrict__ part, const float* __restrict__ partls,
    const float* __restrict__ linT, const float* __restrict__ lin_b,
    const float* __restrict__ wih0, const float* __restrict__ bih0,
    float* __restrict__ gi0)
{
  const int bt = blockIdx.x, j = threadIdx.x;
  __shared__ float sxa[128], shh[128];
  __shared__ float sls;
  if (j < 128) {
    float s = 0.f;
#pragma unroll
    for (int g2 = 0; g2 < 8; g2++) s += part[((size_t)bt * 8 + g2) * 128 + j];
    sxa[j] = s;
  }
  if (j == 128) {
    float s = 0.f;
#pragma unroll
    for (int g2 = 0; g2 < 8; g2++) s += partls[bt * 8 + g2];
    sls = s;
  }
  __syncthreads();
  if (j < 128) {
    float hv = sls * lin_b[j];
#pragma unroll 8
    for (int f2 = 0; f2 < 128; f2++) hv += linT[f2 * 128 + j] * sxa[f2];
    shh[j] = hv;
  }
  __syncthreads();
  const float* wr = wih0 + (size_t)j * 128;
  float gacc = bih0[j];
#pragma unroll 8
  for (int k = 0; k < 128; k++) gacc += wr[k] * shh[k];
  gi0[(size_t)bt * 384 + j] = gacc;
}

// ---------- gi for layer 1
__global__ __launch_bounds__(384, 2) void gi_kernel(
    const float* __restrict__ xin, const float* __restrict__ wih,
    const float* __restrict__ bih, float* __restrict__ gi)
{
  __shared__ __align__(16) float xr[128];
  const int bt = blockIdx.x, j = threadIdx.x;
  if (j < 128) xr[j] = xin[bt * 128 + j];
  __syncthreads();
  const float* wrow = wih + (size_t)j * NH;
  float a0 = 0.f, a1 = 0.f, a2 = 0.f, a3 = 0.f;
#pragma unroll 8
  for (int k = 0; k < 128; k += 4) {
    a0 += wrow[k]     * xr[k];
    a1 += wrow[k + 1] * xr[k + 1];
    a2 += wrow[k + 2] * xr[k + 2];
    a3 += wrow[k + 3] * xr[k + 3];
  }
  gi[(size_t)bt * 384 + j] = (a0 + a1) + (a2 + a3) + bih[j];
}

// ---------- GRU recurrence: gi preloaded to LDS, fast transcendentals
__global__ __launch_bounds__(384, 1) void gru_layer_kernel(
    const float* __restrict__ gi, const float* __restrict__ whh,
    const float* __restrict__ bhh, float* __restrict__ out)
{
  const int b = blockIdx.x, j = threadIdx.x;
  __shared__ float sgi[64 * 384];   // 96 KB
  __shared__ float hs[128], ghs[384];

  const float4* gsrc = (const float4*)(gi + (size_t)b * 64 * 384);
  float4* gdst = (float4*)sgi;
#pragma unroll
  for (int p = 0; p < 16; p++) gdst[p * 384 + j] = gsrc[p * 384 + j];

  float wreg[128];
#pragma unroll
  for (int k = 0; k < 128; k++) wreg[k] = whh[(size_t)j * 128 + k];
  const float bh = bhh[j];
  if (j < 128) hs[j] = 0.f;
  __syncthreads();

  for (int t = 0; t < NT; t++) {
    float a0 = 0.f, a1 = 0.f, a2 = 0.f, a3 = 0.f;
    const float4* h4 = (const float4*)hs;
#pragma unroll
    for (int k = 0; k < 32; k++) {
      float4 hv = h4[k];
      a0 += wreg[4 * k]     * hv.x;
      a1 += wreg[4 * k + 1] * hv.y;
      a2 += wreg[4 * k + 2] * hv.z;
      a3 += wreg[4 * k + 3] * hv.w;
    }
    ghs[j] = (a0 + a1) + (a2 + a3) + bh;
    __syncthreads();
    if (j < 128) {
      const float* gt = &sgi[t * 384];
      const float hprev = hs[j];
      const float r = 1.f / (1.f + __expf(-(gt[j] + ghs[j])));
      const float z = 1.f / (1.f + __expf(-(gt[128 + j] + ghs[128 + j])));
      float nx = gt[256 + j] + r * ghs[256 + j];
      nx = fmaxf(fminf(nx, 15.f), -15.f);
      const float e2 = __expf(2.f * nx);
      const float n = (e2 - 1.f) / (e2 + 1.f);
      const float hnew = (1.f - z) * n + z * hprev;
      hs[j] = hnew;
      out[((size_t)b * NT + t) * 128 + j] = hnew;
    }
    __syncthreads();
  }
}

extern "C" void kernel_launch(void* const* d_in, const int* in_sizes, int n_in,
                              void* d_out, int out_size, void* d_ws, size_t ws_size,
                              hipStream_t stream)
{
  const float* X        = (const float*)d_in[0];
  const float* C        = (const float*)d_in[1];
  const float* h_target = (const float*)d_in[2];
  const float* distance = (const float*)d_in[3];
  const float* lin_w    = (const float*)d_in[4];
  const float* lin_b    = (const float*)d_in[5];
  const float* mlp_w1   = (const float*)d_in[6];
  const float* mlp_b1   = (const float*)d_in[7];
  const float* mlp_w2   = (const float*)d_in[8];
  const float* mlp_b2   = (const float*)d_in[9];
  const float* lin2_w   = (const float*)d_in[10];
  const float* lin2_b   = (const float*)d_in[11];
  const float* wih0     = (const float*)d_in[12];
  const float* whh0     = (const float*)d_in[13];
  const float* bih0     = (const float*)d_in[14];
  const float* bhh0     = (const float*)d_in[15];
  const float* wih1     = (const float*)d_in[16];
  const float* whh1     = (const float*)d_in[17];
  const float* bih1     = (const float*)d_in[18];
  const float* bhh1     = (const float*)d_in[19];
  float* out = (float*)d_out;

  float* ws = (float*)d_ws;
  unsigned short* WxBf = (unsigned short*)ws;        //  16384 bf16  (= 8192 floats)
  float* linT   = ws + 8192;                         //  16384
  float* u_buf  = ws + 24576;                        // 131072
  float* part   = ws + 155648;                       // 8192*128 = 1048576
  float* partls = ws + 1204224;                      //   8192
  float* gi     = ws + 1212416;                      // 393216
  float* out0   = ws + 1605632;                      // 131072   (total ~6.95 MB)

  prep_kernel<<<256, 128, 0, stream>>>(lin_w, mlp_w1, WxBf, linT);
  u_kernel<<<NB * NT, 128, 0, stream>>>(h_target, lin_b, mlp_w1, mlp_b1, u_buf);
  pass1_kernel<<<NB * NT * 8, 256, 0, stream>>>(X, C, distance, WxBf, u_buf,
      mlp_w2, mlp_b2, lin2_w, lin2_b, part, partls);
  reduce_kernel<<<NB * NT, 384, 0, stream>>>(part, partls, linT, lin_b, wih0, bih0, gi);
  gru_layer_kernel<<<NB, 384, 0, stream>>>(gi, whh0, bhh0, out0);
  gi_kernel<<<NB * NT, 384, 0, stream>>>(out0, wih1, bih1, gi);
  gru_layer_kernel<<<NB, 384, 0, stream>>>(gi, whh1, bhh1, out);
}